// Round 8
// baseline (1224.315 us; speedup 1.0000x reference)
//
#include <hip/hip_runtime.h>
#include <math.h>

#define U_ 8192
#define I_ 8192
#define D_ 128
#define E_ 524288
#define N_ 16384
#define K_ 32
#define CAP_ 512

typedef unsigned short u16;
typedef unsigned int u32;
typedef unsigned long long u64;
typedef __attribute__((ext_vector_type(8))) short bf16x8;
typedef __attribute__((ext_vector_type(4))) float f32x4;

// ---------------------------------------------------------------- init ------
__global__ void k_init(const float* __restrict__ wq, const float* __restrict__ wk,
                       const float* __restrict__ bq, const float* __restrict__ wv,
                       float* __restrict__ M, float* __restrict__ bqk,
                       float* __restrict__ wvT,
                       int* __restrict__ cnt, float* __restrict__ cs1,
                       float* __restrict__ cs2, float* __restrict__ C2,
                       float* __restrict__ svec, int* __restrict__ gcount,
                       int* __restrict__ failn) {
  const int tid = blockIdx.x * 256 + threadIdx.x;   // 64 blocks -> 16384 threads
  cnt[tid] = 0;
  gcount[tid] = 0;
  C2[tid] = 0.f;
  if (tid < 128) { cs1[tid] = 0.f; cs2[tid] = 0.f; svec[tid] = 0.f; }
  if (tid == 0) *failn = 0;
  // M[i][j] = sum_l wq[l,i]*wk[l,j]  (wq^T wk)
  const int i = tid >> 7, j = tid & 127;
  float s = 0.f;
  for (int l = 0; l < 128; ++l) s += wq[l * 128 + i] * wk[l * 128 + j];
  M[tid] = s;
  wvT[i * 128 + j] = wv[j * 128 + i];
  if (tid < 128) {
    float s2 = 0.f;
    for (int l = 0; l < 128; ++l) s2 += bq[l] * wk[l * 128 + tid];
    bqk[tid] = s2;
  }
}

__global__ void k_concat(const float* __restrict__ user, const float* __restrict__ item,
                         float* __restrict__ ego) {
  const int i = blockIdx.x * 256 + threadIdx.x;     // 8192 blocks, exact
  ego[i] = (i < U_ * D_) ? user[i] : item[i - U_ * D_];
}

// ---------------------------------------------------------------- CSR -------
__global__ void k_hist(const int* __restrict__ rows, int* __restrict__ cnt) {
  const int e = blockIdx.x * 256 + threadIdx.x;     // 2048 blocks, exact
  atomicAdd(&cnt[rows[e]], 1);
}

__global__ void k_scan(const int* __restrict__ cnt, int* __restrict__ row_ptr,
                       int* __restrict__ cursor) {
  __shared__ int buf[1024];
  __shared__ int carry;
  const int t = threadIdx.x;
  if (t == 0) carry = 0;
  __syncthreads();
  for (int c = 0; c < N_ / 1024; ++c) {
    const int x = cnt[c * 1024 + t];
    buf[t] = x;
    __syncthreads();
    for (int off = 1; off < 1024; off <<= 1) {
      int v = (t >= off) ? buf[t - off] : 0;
      __syncthreads();
      buf[t] += v;
      __syncthreads();
    }
    const int incl = buf[t];
    const int excl = carry + incl - x;
    row_ptr[c * 1024 + t] = excl;
    cursor[c * 1024 + t] = excl;
    __syncthreads();
    if (t == 1023) carry += incl;
    __syncthreads();
  }
  if (t == 0) row_ptr[N_] = carry;
}

__global__ void k_scatter(const int* __restrict__ rows, const int* __restrict__ cols,
                          const float* __restrict__ vals, int* __restrict__ cursor,
                          int* __restrict__ ccol, float* __restrict__ cval) {
  const int e = blockIdx.x * 256 + threadIdx.x;
  const int r = rows[e];
  const int p = atomicAdd(&cursor[r], 1);
  ccol[p] = cols[e];
  cval[p] = vals[e];
}

// ---------------------------------------------------------------- SpMM ------
__global__ __launch_bounds__(128) void k_spmm(const float* __restrict__ x,
                                              float* __restrict__ y,
                                              float* __restrict__ sum,
                                              const int* __restrict__ row_ptr,
                                              const int* __restrict__ ccol,
                                              const float* __restrict__ cval,
                                              const int first) {
  const int r = blockIdx.x, d = threadIdx.x;
  const int b = row_ptr[r], e = row_ptr[r + 1];
  double acc = 0.0;
  for (int i = b; i < e; ++i)
    acc += (double)cval[i] * (double)x[ccol[i] * 128 + d];
  const float f = (float)acc;
  y[r * 128 + d] = f;
  if (first) sum[r * 128 + d] = f; else sum[r * 128 + d] += f;
}

__global__ void k_div3(float* __restrict__ a) {
  const int i = blockIdx.x * 256 + threadIdx.x;
  a[i] = a[i] / 3.0f;
}

// ------------------------------------------------- split + transpose --------
__global__ __launch_bounds__(256) void k_split_t(const float* __restrict__ x,
                                                 u16* __restrict__ Gh, u16* __restrict__ Gl,
                                                 u16* __restrict__ XTh, u16* __restrict__ XTl,
                                                 float* __restrict__ svec) {
  __shared__ u16 lh[128 * 66];
  __shared__ u16 ll[128 * 66];
  const int tid = threadIdx.x;
  const int r0 = blockIdx.x * 64;
  float colsum = 0.f;
  for (int s = 0; s < 32; ++s) {
    const int idx = tid + s * 256;
    const int r = idx >> 7, d = idx & 127;
    const float v = x[(r0 + r) * 128 + d];
    colsum += v;
    unsigned int u = __float_as_uint(v);
    u += 0x7fffu + ((u >> 16) & 1u);
    const u16 h = (u16)(u >> 16);
    const float hf = __uint_as_float(((unsigned int)h) << 16);
    const float l = v - hf;
    unsigned int u2 = __float_as_uint(l);
    u2 += 0x7fffu + ((u2 >> 16) & 1u);
    const u16 lo = (u16)(u2 >> 16);
    Gh[(r0 + r) * 128 + d] = h;
    Gl[(r0 + r) * 128 + d] = lo;
    lh[d * 66 + r] = h;
    ll[d * 66 + r] = lo;
  }
  atomicAdd(&svec[tid & 127], colsum);
  __syncthreads();
  for (int s = 0; s < 32; ++s) {
    const int idx = tid + s * 256;
    const int d = idx >> 6, rr = idx & 63;
    XTh[d * 16384 + r0 + rr] = lh[d * 66 + rr];
    XTl[d * 16384 + r0 + rr] = ll[d * 66 + rr];
  }
}

// ---------------------------------------------------------------- C2 --------
__global__ __launch_bounds__(256) void k_c2mfma(const u16* __restrict__ XTh,
                                                const u16* __restrict__ XTl,
                                                float* __restrict__ C2) {
  const int tid = threadIdx.x, w = tid >> 6, lane = tid & 63;
  const int n16 = lane & 15, kq = lane >> 4;
  const int c0 = blockIdx.x * 512;
  f32x4 acc[2][8];
#pragma unroll
  for (int a = 0; a < 2; ++a)
#pragma unroll
    for (int b = 0; b < 8; ++b) acc[a][b] = (f32x4){0.f, 0.f, 0.f, 0.f};
  for (int ks = 0; ks < 16; ++ks) {
    const int c = c0 + ks * 32 + kq * 8;
    bf16x8 Fh[8], Fl[8];
#pragma unroll
    for (int g = 0; g < 8; ++g) {
      const int base = (g * 16 + n16) * 16384 + c;
      Fh[g] = *(const bf16x8*)&XTh[base];
      Fl[g] = *(const bf16x8*)&XTl[base];
    }
#pragma unroll
    for (int a = 0; a < 2; ++a) {
      const int tr = w * 2 + a;
#pragma unroll
      for (int b = 0; b < 8; ++b) {
        acc[a][b] = __builtin_amdgcn_mfma_f32_16x16x32_bf16(Fl[tr], Fh[b], acc[a][b], 0, 0, 0);
        acc[a][b] = __builtin_amdgcn_mfma_f32_16x16x32_bf16(Fh[tr], Fl[b], acc[a][b], 0, 0, 0);
        acc[a][b] = __builtin_amdgcn_mfma_f32_16x16x32_bf16(Fh[tr], Fh[b], acc[a][b], 0, 0, 0);
      }
    }
  }
#pragma unroll
  for (int a = 0; a < 2; ++a) {
    const int tr = w * 2 + a;
#pragma unroll
    for (int b = 0; b < 8; ++b)
#pragma unroll
      for (int i = 0; i < 4; ++i)
        atomicAdd(&C2[(tr * 16 + kq * 4 + i) * 128 + b * 16 + n16], acc[a][b][i]);
  }
}

// tau_r = mean_r + 2.55 * sigma_r. Containment is STRUCTURAL: count>=36
// guarantees the top-32 (by our scores) all exceed tau; tau only trades
// candidate volume vs fallback frequency.
__global__ __launch_bounds__(128) void k_tau(const float* __restrict__ x,
                                             const float* __restrict__ C2,
                                             const float* __restrict__ svec,
                                             float* __restrict__ tau) {
  __shared__ float xs[128];
  __shared__ double red[128];
  const int n = blockIdx.x, tid = threadIdx.x;
  xs[tid] = x[n * 128 + tid];
  __syncthreads();
  double y = 0.0;
  for (int k2 = 0; k2 < 128; ++k2) y += (double)xs[k2] * (double)C2[k2 * 128 + tid];
  red[tid] = (double)xs[tid] * y;
  __syncthreads();
  for (int s = 64; s; s >>= 1) { if (tid < s) red[tid] += red[tid + s]; __syncthreads(); }
  const double exy = red[0] / 16384.0;
  __syncthreads();
  red[tid] = (double)xs[tid] * (double)svec[tid];
  __syncthreads();
  for (int s = 64; s; s >>= 1) { if (tid < s) red[tid] += red[tid + s]; __syncthreads(); }
  if (tid == 0) {
    const double m = red[0] / 16384.0;
    double var = exy - m * m;
    if (var < 0.0) var = 0.0;
    tau[n] = (float)(m + 2.55 * sqrt(var));
  }
}

// ---------------------------------------------------------------- qk --------
__global__ __launch_bounds__(128) void k_qk(const float* __restrict__ ego,
                                            const float* __restrict__ M,
                                            const float* __restrict__ bqk,
                                            float* __restrict__ qkout) {
  __shared__ float Ml[128 * 128];
  __shared__ float xr[128];
  const int tid = threadIdx.x;
  for (int e = tid; e < 16384; e += 128) Ml[e] = M[e];
  const float bj = bqk[tid];
  for (int r = blockIdx.x; r < N_; r += gridDim.x) {
    __syncthreads();
    xr[tid] = ego[r * 128 + tid];
    __syncthreads();
    float a = bj;
    for (int d = 0; d < 128; ++d) a += xr[d] * Ml[d * 128 + tid];
    qkout[r * 128 + tid] = a;
  }
}

// ------------------------------------------------------- sim via MFMA -------
// 1024 blocks = 64 row-groups (256 rows) x 16 col-strips. Each wave owns
// 64 rows (4 rowgroups, B-frags register-resident); per stage it reads each
// A-fragment once and feeds 4 rowgroups (2x arithmetic intensity vs rg=2).
// Two accumulators per (ct,rg) -> 8 independent MFMA chains per ct for ILP.
// Passers (> tau_r) append (col, fp32 val) to per-row global lists.
__global__ __launch_bounds__(256) void k_simmfma(const u16* __restrict__ Gh,
                                                 const u16* __restrict__ Gl,
                                                 const float* __restrict__ tau,
                                                 int* __restrict__ gcount,
                                                 int2* __restrict__ gbuf) {
  __shared__ u16 lh[64 * 136];
  __shared__ u16 ll[64 * 136];
  const int tid = threadIdx.x;
  const int w = tid >> 6, lane = tid & 63;
  const int strip = blockIdx.x & 15, rgrp = blockIdx.x >> 4;   // rgrp 0..63
  const int n16 = lane & 15, kq = lane >> 4;

  const int rowbase = rgrp * 256 + w * 64;
  bf16x8 Bh[4][4], Bl[4][4];
  float tauv[4];
#pragma unroll
  for (int rg = 0; rg < 4; ++rg) {
    const int row = rowbase + rg * 16 + n16;
#pragma unroll
    for (int q = 0; q < 4; ++q) {
      Bh[rg][q] = *(const bf16x8*)&Gh[row * 128 + q * 32 + kq * 8];
      Bl[rg][q] = *(const bf16x8*)&Gl[row * 128 + q * 32 + kq * 8];
    }
    tauv[rg] = tau[row];
  }
  const int col0 = strip * 1024;
  const int cst = tid >> 2, seg = tid & 3;

  for (int st = 0; st < 16; ++st) {
    const int cb = col0 + st * 64;
    __syncthreads();
#pragma unroll
    for (int i = 0; i < 4; ++i) {
      *(uint4*)&lh[cst * 136 + seg * 32 + i * 8] =
          *(const uint4*)&Gh[(cb + cst) * 128 + seg * 32 + i * 8];
      *(uint4*)&ll[cst * 136 + seg * 32 + i * 8] =
          *(const uint4*)&Gl[(cb + cst) * 128 + seg * 32 + i * 8];
    }
    __syncthreads();
#pragma unroll
    for (int ct = 0; ct < 4; ++ct) {
      bf16x8 Ah[4], Al[4];
#pragma unroll
      for (int q = 0; q < 4; ++q) {
        Ah[q] = *(const bf16x8*)&lh[(ct * 16 + n16) * 136 + q * 32 + kq * 8];
        Al[q] = *(const bf16x8*)&ll[(ct * 16 + n16) * 136 + q * 32 + kq * 8];
      }
#pragma unroll
      for (int rg = 0; rg < 4; ++rg) {
        f32x4 p = {0.f, 0.f, 0.f, 0.f};
        f32x4 r = {0.f, 0.f, 0.f, 0.f};
#pragma unroll
        for (int q = 0; q < 4; ++q) {
          p = __builtin_amdgcn_mfma_f32_16x16x32_bf16(Ah[q], Bh[rg][q], p, 0, 0, 0);
          r = __builtin_amdgcn_mfma_f32_16x16x32_bf16(Ah[q], Bl[rg][q], r, 0, 0, 0);
          r = __builtin_amdgcn_mfma_f32_16x16x32_bf16(Al[q], Bh[rg][q], r, 0, 0, 0);
        }
        const float tv = tauv[rg];
        const int row = rowbase + rg * 16 + n16;
#pragma unroll
        for (int i = 0; i < 4; ++i) {
          const float v = p[i] + r[i];
          if (v > tv) {
            const int c = cb + ct * 16 + kq * 4 + i;
            const int pos = atomicAdd(&gcount[row], 1);
            if (pos < CAP_) gbuf[row * CAP_ + pos] = make_int2(c, __float_as_int(v));
          }
        }
      }
    }
  }
}

// rows whose candidate count violates [36,CAP_] go to the exact fallback
__global__ void k_check(const int* __restrict__ gcount, int* __restrict__ failq,
                        int* __restrict__ failn) {
  const int n = blockIdx.x * 256 + threadIdx.x;   // 64 blocks
  const int c = gcount[n];
  if (c < 36 || c > CAP_) {
    const int s = atomicAdd(failn, 1);
    if (s < 64) failq[s] = n;
  }
}

// Top-32 by stored fp32 sim values via RANK-SCATTER on packed u64 keys:
// key = (sortable_f32 << 32) | (16383 - col)  -> (val desc, col asc) order.
// rank = #{keys greater}; rank<32 scatters directly. One wave per row.
__global__ __launch_bounds__(256) void k_refine(const int* __restrict__ gcount,
                                                const int2* __restrict__ gbuf,
                                                int* __restrict__ topk_idx) {
  __shared__ u64 lk[4][CAP_];
  const int tid = threadIdx.x, w = tid >> 6, lane = tid & 63;
  const int n = blockIdx.x * 4 + w;
  const int craw = gcount[n];
  const int bad = (craw < 36 || craw > CAP_);
  const int cnt = bad ? 0 : craw;

  u64 ku[CAP_ / 64];
  int kc[CAP_ / 64];
#pragma unroll
  for (int s = 0; s < CAP_ / 64; ++s) {
    ku[s] = 0; kc[s] = 0;
    const int ci = lane + s * 64;
    if (ci < cnt) {
      const int2 p = gbuf[n * CAP_ + ci];
      u32 uv = (u32)p.y;
      uv = (uv >> 31) ? ~uv : (uv | 0x80000000u);
      const u64 key = ((u64)uv << 32) | (u64)(16383 - p.x);
      lk[w][ci] = key;
      ku[s] = key;
      kc[s] = p.x;
    }
  }
  __syncthreads();

#pragma unroll
  for (int s = 0; s < CAP_ / 64; ++s) {
    const int ci = lane + s * 64;
    if (ci < cnt) {
      const u64 kk = ku[s];
      int r = 0;
#pragma unroll 4
      for (int j = 0; j < cnt; ++j)
        r += (lk[w][j] > kk) ? 1 : 0;
      if (r < 32) topk_idx[n * 32 + r] = kc[s];
    }
  }
  if (bad && lane < 32) topk_idx[n * 32 + lane] = 0;  // placeholder; fallback overwrites
}

// exact fp64 full-row top-32 for statistically-failed rows (expected: none)
__global__ __launch_bounds__(256) void k_fallback(const float* __restrict__ x,
                                                  const int* __restrict__ failq,
                                                  const int* __restrict__ failn,
                                                  double* __restrict__ fsim,
                                                  int* __restrict__ topk_idx) {
  const int nf = *failn;
  const int which = blockIdx.x;
  if (which >= nf || which >= 64) return;
  const int row = failq[which];
  __shared__ float xs[128];
  __shared__ double bm[256];
  __shared__ int bc[256];
  const int tid = threadIdx.x;
  if (tid < 128) xs[tid] = x[row * 128 + tid];
  __syncthreads();
  double* fs = fsim + (size_t)which * 16384;
  for (int c = tid; c < 16384; c += 256) {
    const float4* xp = (const float4*)&x[c * 128];
    double a = 0.0;
    for (int d = 0; d < 32; ++d) {
      const float4 v = xp[d];
      a += (double)xs[d * 4 + 0] * (double)v.x + (double)xs[d * 4 + 1] * (double)v.y +
           (double)xs[d * 4 + 2] * (double)v.z + (double)xs[d * 4 + 3] * (double)v.w;
    }
    fs[c] = a;
  }
  __syncthreads();
  for (int r = 0; r < 32; ++r) {
    double m = -1.0e300; int mc = 0;
    for (int c = tid; c < 16384; c += 256) {
      const double v = fs[c];
      if (v > m || (v == m && c < mc)) { m = v; mc = c; }
    }
    bm[tid] = m; bc[tid] = mc;
    __syncthreads();
    for (int s = 128; s; s >>= 1) {
      if (tid < s) {
        if (bm[tid + s] > bm[tid] || (bm[tid + s] == bm[tid] && bc[tid + s] < bc[tid])) {
          bm[tid] = bm[tid + s]; bc[tid] = bc[tid + s];
        }
      }
      __syncthreads();
    }
    if (tid == 0) { topk_idx[row * 32 + r] = bc[0]; fs[bc[0]] = -1.0e300; }
    __syncthreads();
  }
}

// ------------------------------------------------------- attention ----------
__global__ __launch_bounds__(128) void k_attn(const float* __restrict__ ego,
                                              const float* __restrict__ qk,
                                              const int* __restrict__ topk_idx,
                                              const float* __restrict__ wvT,
                                              const float* __restrict__ bv,
                                              float* __restrict__ atten) {
  __shared__ float qv[128];
  __shared__ float sm[32 * 129];
  __shared__ int tki[32];
  __shared__ float sc[32];
  __shared__ float sa[128];
  __shared__ float psum[128];
  const int n = blockIdx.x, tid = threadIdx.x;
  qv[tid] = qk[n * 128 + tid];
  if (tid < 32) tki[tid] = topk_idx[n * 32 + tid] & 16383;
  __syncthreads();
  for (int e = tid; e < 32 * 128; e += 128) {
    const int k2 = e >> 7, d = e & 127;
    sm[k2 * 129 + d] = ego[tki[k2] * 128 + d];
  }
  __syncthreads();
  {
    const int kk = tid & 31, part = tid >> 5;
    float s = 0.f;
    const int d0 = part * 32;
    for (int d = d0; d < d0 + 32; ++d) s += qv[d] * sm[kk * 129 + d];
    psum[tid] = s;
  }
  __syncthreads();
  if (tid < 32) {
    float v = psum[tid] + psum[tid + 32] + psum[tid + 64] + psum[tid + 96];
    v *= (1.0f / 11.313708498984760f);    // 1/sqrt(128)
    float m = v;
#pragma unroll
    for (int off = 16; off; off >>= 1) m = fmaxf(m, __shfl_xor(m, off, 32));
    const float e = expf(v - m);
    float ssum = e;
#pragma unroll
    for (int off = 16; off; off >>= 1) ssum += __shfl_xor(ssum, off, 32);
    sc[tid] = e / ssum;
  }
  __syncthreads();
  float sad = 0.f;
  for (int k2 = 0; k2 < 32; ++k2) sad += sc[k2] * sm[k2 * 129 + tid];
  sa[tid] = sad;
  __syncthreads();
  float o = bv[tid];
  for (int d = 0; d < 128; ++d) o += sa[d] * wvT[d * 128 + tid];
  atten[n * 128 + tid] = o + 0.1f * ego[n * 128 + tid];
}

// ------------------------------------------------------- fusion -------------
__global__ __launch_bounds__(128) void k_fuse1(const float* __restrict__ allemb,
                                               const float* __restrict__ atten,
                                               const float* __restrict__ fw,
                                               const float* __restrict__ fb,
                                               float* __restrict__ z1,
                                               float* __restrict__ z2,
                                               float* __restrict__ cs1,
                                               float* __restrict__ cs2) {
  __shared__ float fwT[128 * 129];
  __shared__ float xr[128], ar[128];
  const int tid = threadIdx.x;
  for (int it = 0; it < 128; ++it) fwT[tid * 129 + it] = fw[it * 128 + tid];
  const float fbj = fb[tid];
  float ls1 = 0.f, ls2 = 0.f;
  const int r0 = blockIdx.x * 64;
  for (int rr = 0; rr < 64; ++rr) {
    const int r = r0 + rr;
    __syncthreads();
    xr[tid] = allemb[r * 128 + tid];
    ar[tid] = atten[r * 128 + tid];
    __syncthreads();
    float a1 = fbj, a2 = fbj;
    for (int d = 0; d < 128; ++d) {
      const float wgt = fwT[d * 129 + tid];
      a1 += xr[d] * wgt;
      a2 += ar[d] * wgt;
    }
    const float t1 = tanhf(a1), t2 = tanhf(a2);
    z1[r * 128 + tid] = t1;
    z2[r * 128 + tid] = t2;
    ls1 += expf(t1 - 1.0f);
    ls2 += expf(t2 - 1.0f);
  }
  atomicAdd(&cs1[tid], ls1);
  atomicAdd(&cs2[tid], ls2);
}

__global__ void k_fuse2(const float* __restrict__ allemb, const float* __restrict__ atten,
                        const float* __restrict__ z1, const float* __restrict__ z2,
                        const float* __restrict__ cs1, const float* __restrict__ cs2,
                        float* __restrict__ fusion) {
  const int i = blockIdx.x * 256 + threadIdx.x;
  const int j = i & 127;
  const float a1 = expf(z1[i] - 1.0f) / cs1[j];
  const float a2 = expf(z2[i] - 1.0f) / cs2[j];
  fusion[i] = a1 * allemb[i] + a2 * atten[i];
}

// ---------------------------------------------------------------- launch ----
extern "C" void kernel_launch(void* const* d_in, const int* in_sizes, int n_in,
                              void* d_out, int out_size, void* d_ws, size_t ws_size,
                              hipStream_t stream) {
  (void)in_sizes; (void)n_in; (void)out_size; (void)ws_size;
  const float* user = (const float*)d_in[0];
  const float* item = (const float*)d_in[1];
  const int* adj_rows = (const int*)d_in[2];
  const int* adj_cols = (const int*)d_in[3];
  const float* adj_vals = (const float*)d_in[4];
  const float* wq = (const float*)d_in[5];
  const float* bq = (const float*)d_in[6];
  const float* wk = (const float*)d_in[7];
  const float* wv = (const float*)d_in[9];
  const float* bv = (const float*)d_in[10];
  const float* fw = (const float*)d_in[11];
  const float* fb = (const float*)d_in[12];

  float* out = (float*)d_out;
  float* allemb = out;                    // [N,D]
  float* atten = out + (size_t)N_ * D_;   // [N,D]
  float* fusion = out + (size_t)2 * N_ * D_;

  char* ws = (char*)d_ws;
  size_t off = 0;
  auto alloc = [&](size_t bytes) { char* p = ws + off; off += (bytes + 255) & ~(size_t)255; return p; };
  float* ego_a = (float*)alloc((size_t)N_ * D_ * 4);
  float* ego_b = (float*)alloc((size_t)N_ * D_ * 4);
  float* qkbuf = (float*)alloc((size_t)N_ * D_ * 4);
  u16* Gh = (u16*)alloc((size_t)N_ * D_ * 2);
  u16* Gl = (u16*)alloc((size_t)N_ * D_ * 2);
  u16* XTh = (u16*)alloc((size_t)N_ * D_ * 2);
  u16* XTl = (u16*)alloc((size_t)N_ * D_ * 2);
  int2* gbuf = (int2*)alloc((size_t)N_ * CAP_ * 8);  // (col,val) pairs (aliased by z1)
  float* z1 = (float*)gbuf;                          // lifetimes disjoint
  float* z2 = (float*)alloc((size_t)N_ * D_ * 4);
  int* topk_idx = (int*)alloc((size_t)N_ * 32 * 4);
  int* ccol = (int*)alloc((size_t)E_ * 4);
  float* cval = (float*)alloc((size_t)E_ * 4);
  int* cnt = (int*)alloc((size_t)N_ * 4);
  int* row_ptr = (int*)alloc((size_t)(N_ + 1) * 4);
  int* cursor = (int*)alloc((size_t)N_ * 4);
  float* M = (float*)alloc(128 * 128 * 4);
  float* bqk = (float*)alloc(128 * 4);
  float* wvT = (float*)alloc(128 * 128 * 4);
  float* cs1 = (float*)alloc(128 * 4);
  float* cs2 = (float*)alloc(128 * 4);
  float* C2 = (float*)alloc(128 * 128 * 4);
  float* svec = (float*)alloc(128 * 4);
  float* tau = (float*)alloc((size_t)N_ * 4);
  int* gcount = (int*)alloc((size_t)N_ * 4);
  int* failq = (int*)alloc(64 * 4);
  int* failn = (int*)alloc(4);
  double* fsim = (double*)alloc((size_t)64 * N_ * 8);

  k_init<<<64, 256, 0, stream>>>(wq, wk, bq, wv, M, bqk, wvT, cnt, cs1, cs2, C2, svec, gcount, failn);
  k_concat<<<8192, 256, 0, stream>>>(user, item, ego_a);
  k_hist<<<2048, 256, 0, stream>>>(adj_rows, cnt);
  k_scan<<<1, 1024, 0, stream>>>(cnt, row_ptr, cursor);
  k_scatter<<<2048, 256, 0, stream>>>(adj_rows, adj_cols, adj_vals, cursor, ccol, cval);

  k_spmm<<<N_, 128, 0, stream>>>(ego_a, ego_b, allemb, row_ptr, ccol, cval, 1);
  k_spmm<<<N_, 128, 0, stream>>>(ego_b, ego_a, allemb, row_ptr, ccol, cval, 0);
  k_spmm<<<N_, 128, 0, stream>>>(ego_a, ego_b, allemb, row_ptr, ccol, cval, 0);
  // ego3 = ego_b
  k_div3<<<8192, 256, 0, stream>>>(allemb);

  k_split_t<<<256, 256, 0, stream>>>(ego_b, Gh, Gl, XTh, XTl, svec);
  k_c2mfma<<<32, 256, 0, stream>>>(XTh, XTl, C2);
  k_tau<<<N_, 128, 0, stream>>>(ego_b, C2, svec, tau);

  k_qk<<<512, 128, 0, stream>>>(ego_b, M, bqk, qkbuf);
  k_simmfma<<<1024, 256, 0, stream>>>(Gh, Gl, tau, gcount, gbuf);
  k_check<<<64, 256, 0, stream>>>(gcount, failq, failn);
  k_refine<<<4096, 256, 0, stream>>>(gcount, gbuf, topk_idx);
  k_fallback<<<64, 256, 0, stream>>>(ego_b, failq, failn, fsim, topk_idx);
  k_attn<<<N_, 128, 0, stream>>>(ego_b, qkbuf, topk_idx, wvT, bv, atten);

  k_fuse1<<<256, 128, 0, stream>>>(allemb, atten, fw, fb, z1, z2, cs1, cs2);
  k_fuse2<<<8192, 256, 0, stream>>>(allemb, atten, z1, z2, cs1, cs2, fusion);
}

// Round 9
// 1063.013 us; speedup vs baseline: 1.1517x; 1.1517x over previous
//
#include <hip/hip_runtime.h>
#include <math.h>

#define U_ 8192
#define I_ 8192
#define D_ 128
#define E_ 524288
#define N_ 16384
#define K_ 32
#define CAP_ 512

typedef unsigned short u16;
typedef unsigned int u32;
typedef unsigned long long u64;
typedef __attribute__((ext_vector_type(8))) short bf16x8;
typedef __attribute__((ext_vector_type(4))) float f32x4;

// ---------------------------------------------------------------- init ------
__global__ void k_init(const float* __restrict__ wq, const float* __restrict__ wk,
                       const float* __restrict__ bq, const float* __restrict__ wv,
                       float* __restrict__ M, float* __restrict__ bqk,
                       float* __restrict__ wvT,
                       int* __restrict__ cnt, float* __restrict__ cs1,
                       float* __restrict__ cs2, float* __restrict__ C2,
                       float* __restrict__ svec, int* __restrict__ gcount,
                       int* __restrict__ failn) {
  const int tid = blockIdx.x * 256 + threadIdx.x;   // 64 blocks -> 16384 threads
  cnt[tid] = 0;
  gcount[tid] = 0;
  C2[tid] = 0.f;
  if (tid < 128) { cs1[tid] = 0.f; cs2[tid] = 0.f; svec[tid] = 0.f; }
  if (tid == 0) *failn = 0;
  // M[i][j] = sum_l wq[l,i]*wk[l,j]  (wq^T wk)
  const int i = tid >> 7, j = tid & 127;
  float s = 0.f;
  for (int l = 0; l < 128; ++l) s += wq[l * 128 + i] * wk[l * 128 + j];
  M[tid] = s;
  wvT[i * 128 + j] = wv[j * 128 + i];
  if (tid < 128) {
    float s2 = 0.f;
    for (int l = 0; l < 128; ++l) s2 += bq[l] * wk[l * 128 + tid];
    bqk[tid] = s2;
  }
}

__global__ void k_concat(const float* __restrict__ user, const float* __restrict__ item,
                         float* __restrict__ ego) {
  const int i = blockIdx.x * 256 + threadIdx.x;     // 8192 blocks, exact
  ego[i] = (i < U_ * D_) ? user[i] : item[i - U_ * D_];
}

// ---------------------------------------------------------------- CSR -------
__global__ void k_hist(const int* __restrict__ rows, int* __restrict__ cnt) {
  const int e = blockIdx.x * 256 + threadIdx.x;     // 2048 blocks, exact
  atomicAdd(&cnt[rows[e]], 1);
}

__global__ void k_scan(const int* __restrict__ cnt, int* __restrict__ row_ptr,
                       int* __restrict__ cursor) {
  __shared__ int buf[1024];
  __shared__ int carry;
  const int t = threadIdx.x;
  if (t == 0) carry = 0;
  __syncthreads();
  for (int c = 0; c < N_ / 1024; ++c) {
    const int x = cnt[c * 1024 + t];
    buf[t] = x;
    __syncthreads();
    for (int off = 1; off < 1024; off <<= 1) {
      int v = (t >= off) ? buf[t - off] : 0;
      __syncthreads();
      buf[t] += v;
      __syncthreads();
    }
    const int incl = buf[t];
    const int excl = carry + incl - x;
    row_ptr[c * 1024 + t] = excl;
    cursor[c * 1024 + t] = excl;
    __syncthreads();
    if (t == 1023) carry += incl;
    __syncthreads();
  }
  if (t == 0) row_ptr[N_] = carry;
}

__global__ void k_scatter(const int* __restrict__ rows, const int* __restrict__ cols,
                          const float* __restrict__ vals, int* __restrict__ cursor,
                          int* __restrict__ ccol, float* __restrict__ cval) {
  const int e = blockIdx.x * 256 + threadIdx.x;
  const int r = rows[e];
  const int p = atomicAdd(&cursor[r], 1);
  ccol[p] = cols[e];
  cval[p] = vals[e];
}

// ---------------------------------------------------------------- SpMM ------
__global__ __launch_bounds__(128) void k_spmm(const float* __restrict__ x,
                                              float* __restrict__ y,
                                              float* __restrict__ sum,
                                              const int* __restrict__ row_ptr,
                                              const int* __restrict__ ccol,
                                              const float* __restrict__ cval,
                                              const int first) {
  const int r = blockIdx.x, d = threadIdx.x;
  const int b = row_ptr[r], e = row_ptr[r + 1];
  double acc = 0.0;
  for (int i = b; i < e; ++i)
    acc += (double)cval[i] * (double)x[ccol[i] * 128 + d];
  const float f = (float)acc;
  y[r * 128 + d] = f;
  if (first) sum[r * 128 + d] = f; else sum[r * 128 + d] += f;
}

__global__ void k_div3(float* __restrict__ a) {
  const int i = blockIdx.x * 256 + threadIdx.x;
  a[i] = a[i] / 3.0f;
}

// ------------------------------------------------- split + transpose --------
__global__ __launch_bounds__(256) void k_split_t(const float* __restrict__ x,
                                                 u16* __restrict__ Gh, u16* __restrict__ Gl,
                                                 u16* __restrict__ XTh, u16* __restrict__ XTl,
                                                 float* __restrict__ svec) {
  __shared__ u16 lh[128 * 66];
  __shared__ u16 ll[128 * 66];
  const int tid = threadIdx.x;
  const int r0 = blockIdx.x * 64;
  float colsum = 0.f;
  for (int s = 0; s < 32; ++s) {
    const int idx = tid + s * 256;
    const int r = idx >> 7, d = idx & 127;
    const float v = x[(r0 + r) * 128 + d];
    colsum += v;
    unsigned int u = __float_as_uint(v);
    u += 0x7fffu + ((u >> 16) & 1u);
    const u16 h = (u16)(u >> 16);
    const float hf = __uint_as_float(((unsigned int)h) << 16);
    const float l = v - hf;
    unsigned int u2 = __float_as_uint(l);
    u2 += 0x7fffu + ((u2 >> 16) & 1u);
    const u16 lo = (u16)(u2 >> 16);
    Gh[(r0 + r) * 128 + d] = h;
    Gl[(r0 + r) * 128 + d] = lo;
    lh[d * 66 + r] = h;
    ll[d * 66 + r] = lo;
  }
  atomicAdd(&svec[tid & 127], colsum);
  __syncthreads();
  for (int s = 0; s < 32; ++s) {
    const int idx = tid + s * 256;
    const int d = idx >> 6, rr = idx & 63;
    XTh[d * 16384 + r0 + rr] = lh[d * 66 + rr];
    XTl[d * 16384 + r0 + rr] = ll[d * 66 + rr];
  }
}

// ---------------------------------------------------------------- C2 --------
__global__ __launch_bounds__(256) void k_c2mfma(const u16* __restrict__ XTh,
                                                const u16* __restrict__ XTl,
                                                float* __restrict__ C2) {
  const int tid = threadIdx.x, w = tid >> 6, lane = tid & 63;
  const int n16 = lane & 15, kq = lane >> 4;
  const int c0 = blockIdx.x * 512;
  f32x4 acc[2][8];
#pragma unroll
  for (int a = 0; a < 2; ++a)
#pragma unroll
    for (int b = 0; b < 8; ++b) acc[a][b] = (f32x4){0.f, 0.f, 0.f, 0.f};
  for (int ks = 0; ks < 16; ++ks) {
    const int c = c0 + ks * 32 + kq * 8;
    bf16x8 Fh[8], Fl[8];
#pragma unroll
    for (int g = 0; g < 8; ++g) {
      const int base = (g * 16 + n16) * 16384 + c;
      Fh[g] = *(const bf16x8*)&XTh[base];
      Fl[g] = *(const bf16x8*)&XTl[base];
    }
#pragma unroll
    for (int a = 0; a < 2; ++a) {
      const int tr = w * 2 + a;
#pragma unroll
      for (int b = 0; b < 8; ++b) {
        acc[a][b] = __builtin_amdgcn_mfma_f32_16x16x32_bf16(Fl[tr], Fh[b], acc[a][b], 0, 0, 0);
        acc[a][b] = __builtin_amdgcn_mfma_f32_16x16x32_bf16(Fh[tr], Fl[b], acc[a][b], 0, 0, 0);
        acc[a][b] = __builtin_amdgcn_mfma_f32_16x16x32_bf16(Fh[tr], Fh[b], acc[a][b], 0, 0, 0);
      }
    }
  }
#pragma unroll
  for (int a = 0; a < 2; ++a) {
    const int tr = w * 2 + a;
#pragma unroll
    for (int b = 0; b < 8; ++b)
#pragma unroll
      for (int i = 0; i < 4; ++i)
        atomicAdd(&C2[(tr * 16 + kq * 4 + i) * 128 + b * 16 + n16], acc[a][b][i]);
  }
}

// tau_r = mean_r + 2.55 * sigma_r. Containment is STRUCTURAL: count>=36
// guarantees the top-32 (by our scores) all exceed tau; tau only trades
// candidate volume vs fallback frequency.
__global__ __launch_bounds__(128) void k_tau(const float* __restrict__ x,
                                             const float* __restrict__ C2,
                                             const float* __restrict__ svec,
                                             float* __restrict__ tau) {
  __shared__ float xs[128];
  __shared__ double red[128];
  const int n = blockIdx.x, tid = threadIdx.x;
  xs[tid] = x[n * 128 + tid];
  __syncthreads();
  double y = 0.0;
  for (int k2 = 0; k2 < 128; ++k2) y += (double)xs[k2] * (double)C2[k2 * 128 + tid];
  red[tid] = (double)xs[tid] * y;
  __syncthreads();
  for (int s = 64; s; s >>= 1) { if (tid < s) red[tid] += red[tid + s]; __syncthreads(); }
  const double exy = red[0] / 16384.0;
  __syncthreads();
  red[tid] = (double)xs[tid] * (double)svec[tid];
  __syncthreads();
  for (int s = 64; s; s >>= 1) { if (tid < s) red[tid] += red[tid + s]; __syncthreads(); }
  if (tid == 0) {
    const double m = red[0] / 16384.0;
    double var = exy - m * m;
    if (var < 0.0) var = 0.0;
    tau[n] = (float)(m + 2.55 * sqrt(var));
  }
}

// ---------------------------------------------------------------- qk --------
__global__ __launch_bounds__(128) void k_qk(const float* __restrict__ ego,
                                            const float* __restrict__ M,
                                            const float* __restrict__ bqk,
                                            float* __restrict__ qkout) {
  __shared__ float Ml[128 * 128];
  __shared__ float xr[128];
  const int tid = threadIdx.x;
  for (int e = tid; e < 16384; e += 128) Ml[e] = M[e];
  const float bj = bqk[tid];
  for (int r = blockIdx.x; r < N_; r += gridDim.x) {
    __syncthreads();
    xr[tid] = ego[r * 128 + tid];
    __syncthreads();
    float a = bj;
    for (int d = 0; d < 128; ++d) a += xr[d] * Ml[d * 128 + tid];
    qkout[r * 128 + tid] = a;
  }
}

// ------------------------------------------------------- sim via MFMA -------
// Round-7 structure (rg=2, 2048 blocks, B-frags register-resident) with the
// A-side low-half correction DROPPED: sim ~= Ah.Bh + Ah.Bl. A-lo error
// ~0.002*sigma_sim (8e-11 abs) — below numpy fp32's own rounding noise and
// far below the tau containment margin; fallback net still guards. Only the
// HI A-tile is staged in LDS (half the LDS traffic/capacity of round 7).
__global__ __launch_bounds__(256) void k_simmfma(const u16* __restrict__ Gh,
                                                 const u16* __restrict__ Gl,
                                                 const float* __restrict__ tau,
                                                 int* __restrict__ gcount,
                                                 int2* __restrict__ gbuf) {
  __shared__ u16 lh[64 * 136];
  const int tid = threadIdx.x;
  const int w = tid >> 6, lane = tid & 63;
  const int strip = blockIdx.x & 15, rgrp = blockIdx.x >> 4;
  const int n16 = lane & 15, kq = lane >> 4;

  const int rowbase = rgrp * 128 + w * 32;
  bf16x8 Bh[2][4], Bl[2][4];
#pragma unroll
  for (int rg = 0; rg < 2; ++rg) {
    const int row = rowbase + rg * 16 + n16;
#pragma unroll
    for (int q = 0; q < 4; ++q) {
      Bh[rg][q] = *(const bf16x8*)&Gh[row * 128 + q * 32 + kq * 8];
      Bl[rg][q] = *(const bf16x8*)&Gl[row * 128 + q * 32 + kq * 8];
    }
  }
  const float tau0 = tau[rowbase + n16];
  const float tau1 = tau[rowbase + 16 + n16];
  const int col0 = strip * 1024;
  const int cst = tid >> 2, seg = tid & 3;

  for (int st = 0; st < 16; ++st) {
    const int cb = col0 + st * 64;
    __syncthreads();
#pragma unroll
    for (int i = 0; i < 4; ++i) {
      *(uint4*)&lh[cst * 136 + seg * 32 + i * 8] =
          *(const uint4*)&Gh[(cb + cst) * 128 + seg * 32 + i * 8];
    }
    __syncthreads();
#pragma unroll
    for (int ct = 0; ct < 4; ++ct) {
      bf16x8 Ah[4];
#pragma unroll
      for (int q = 0; q < 4; ++q)
        Ah[q] = *(const bf16x8*)&lh[(ct * 16 + n16) * 136 + q * 32 + kq * 8];
#pragma unroll
      for (int rg = 0; rg < 2; ++rg) {
        f32x4 p = {0.f, 0.f, 0.f, 0.f};
        f32x4 r = {0.f, 0.f, 0.f, 0.f};
#pragma unroll
        for (int q = 0; q < 4; ++q) {
          p = __builtin_amdgcn_mfma_f32_16x16x32_bf16(Ah[q], Bh[rg][q], p, 0, 0, 0);
          r = __builtin_amdgcn_mfma_f32_16x16x32_bf16(Ah[q], Bl[rg][q], r, 0, 0, 0);
        }
        const float tv = rg ? tau1 : tau0;
        const int row = rowbase + rg * 16 + n16;
#pragma unroll
        for (int i = 0; i < 4; ++i) {
          const float v = p[i] + r[i];
          if (v > tv) {
            const int c = cb + ct * 16 + kq * 4 + i;
            const int pos = atomicAdd(&gcount[row], 1);
            if (pos < CAP_) gbuf[row * CAP_ + pos] = make_int2(c, __float_as_int(v));
          }
        }
      }
    }
  }
}

// rows whose candidate count violates [36,CAP_] go to the exact fallback
__global__ void k_check(const int* __restrict__ gcount, int* __restrict__ failq,
                        int* __restrict__ failn) {
  const int n = blockIdx.x * 256 + threadIdx.x;   // 64 blocks
  const int c = gcount[n];
  if (c < 36 || c > CAP_) {
    const int s = atomicAdd(failn, 1);
    if (s < 64) failq[s] = n;
  }
}

// Top-32 by stored fp32 sim values via RANK-SCATTER on packed u64 keys:
// key = (sortable_f32 << 32) | (16383 - col)  -> (val desc, col asc) order.
// rank = #{keys greater}; rank<32 scatters directly. One wave per row.
__global__ __launch_bounds__(256) void k_refine(const int* __restrict__ gcount,
                                                const int2* __restrict__ gbuf,
                                                int* __restrict__ topk_idx) {
  __shared__ u64 lk[4][CAP_];
  const int tid = threadIdx.x, w = tid >> 6, lane = tid & 63;
  const int n = blockIdx.x * 4 + w;
  const int craw = gcount[n];
  const int bad = (craw < 36 || craw > CAP_);
  const int cnt = bad ? 0 : craw;

  u64 ku[CAP_ / 64];
  int kc[CAP_ / 64];
#pragma unroll
  for (int s = 0; s < CAP_ / 64; ++s) {
    ku[s] = 0; kc[s] = 0;
    const int ci = lane + s * 64;
    if (ci < cnt) {
      const int2 p = gbuf[n * CAP_ + ci];
      u32 uv = (u32)p.y;
      uv = (uv >> 31) ? ~uv : (uv | 0x80000000u);
      const u64 key = ((u64)uv << 32) | (u64)(16383 - p.x);
      lk[w][ci] = key;
      ku[s] = key;
      kc[s] = p.x;
    }
  }
  __syncthreads();

#pragma unroll
  for (int s = 0; s < CAP_ / 64; ++s) {
    const int ci = lane + s * 64;
    if (ci < cnt) {
      const u64 kk = ku[s];
      int r = 0;
#pragma unroll 4
      for (int j = 0; j < cnt; ++j)
        r += (lk[w][j] > kk) ? 1 : 0;
      if (r < 32) topk_idx[n * 32 + r] = kc[s];
    }
  }
  if (bad && lane < 32) topk_idx[n * 32 + lane] = 0;  // placeholder; fallback overwrites
}

// exact fp64 full-row top-32 for statistically-failed rows (expected: none)
__global__ __launch_bounds__(256) void k_fallback(const float* __restrict__ x,
                                                  const int* __restrict__ failq,
                                                  const int* __restrict__ failn,
                                                  double* __restrict__ fsim,
                                                  int* __restrict__ topk_idx) {
  const int nf = *failn;
  const int which = blockIdx.x;
  if (which >= nf || which >= 64) return;
  const int row = failq[which];
  __shared__ float xs[128];
  __shared__ double bm[256];
  __shared__ int bc[256];
  const int tid = threadIdx.x;
  if (tid < 128) xs[tid] = x[row * 128 + tid];
  __syncthreads();
  double* fs = fsim + (size_t)which * 16384;
  for (int c = tid; c < 16384; c += 256) {
    const float4* xp = (const float4*)&x[c * 128];
    double a = 0.0;
    for (int d = 0; d < 32; ++d) {
      const float4 v = xp[d];
      a += (double)xs[d * 4 + 0] * (double)v.x + (double)xs[d * 4 + 1] * (double)v.y +
           (double)xs[d * 4 + 2] * (double)v.z + (double)xs[d * 4 + 3] * (double)v.w;
    }
    fs[c] = a;
  }
  __syncthreads();
  for (int r = 0; r < 32; ++r) {
    double m = -1.0e300; int mc = 0;
    for (int c = tid; c < 16384; c += 256) {
      const double v = fs[c];
      if (v > m || (v == m && c < mc)) { m = v; mc = c; }
    }
    bm[tid] = m; bc[tid] = mc;
    __syncthreads();
    for (int s = 128; s; s >>= 1) {
      if (tid < s) {
        if (bm[tid + s] > bm[tid] || (bm[tid + s] == bm[tid] && bc[tid + s] < bc[tid])) {
          bm[tid] = bm[tid + s]; bc[tid] = bc[tid + s];
        }
      }
      __syncthreads();
    }
    if (tid == 0) { topk_idx[row * 32 + r] = bc[0]; fs[bc[0]] = -1.0e300; }
    __syncthreads();
  }
}

// ------------------------------------------------------- attention ----------
__global__ __launch_bounds__(128) void k_attn(const float* __restrict__ ego,
                                              const float* __restrict__ qk,
                                              const int* __restrict__ topk_idx,
                                              const float* __restrict__ wvT,
                                              const float* __restrict__ bv,
                                              float* __restrict__ atten) {
  __shared__ float qv[128];
  __shared__ float sm[32 * 129];
  __shared__ int tki[32];
  __shared__ float sc[32];
  __shared__ float sa[128];
  __shared__ float psum[128];
  const int n = blockIdx.x, tid = threadIdx.x;
  qv[tid] = qk[n * 128 + tid];
  if (tid < 32) tki[tid] = topk_idx[n * 32 + tid] & 16383;
  __syncthreads();
  for (int e = tid; e < 32 * 128; e += 128) {
    const int k2 = e >> 7, d = e & 127;
    sm[k2 * 129 + d] = ego[tki[k2] * 128 + d];
  }
  __syncthreads();
  {
    const int kk = tid & 31, part = tid >> 5;
    float s = 0.f;
    const int d0 = part * 32;
    for (int d = d0; d < d0 + 32; ++d) s += qv[d] * sm[kk * 129 + d];
    psum[tid] = s;
  }
  __syncthreads();
  if (tid < 32) {
    float v = psum[tid] + psum[tid + 32] + psum[tid + 64] + psum[tid + 96];
    v *= (1.0f / 11.313708498984760f);    // 1/sqrt(128)
    float m = v;
#pragma unroll
    for (int off = 16; off; off >>= 1) m = fmaxf(m, __shfl_xor(m, off, 32));
    const float e = expf(v - m);
    float ssum = e;
#pragma unroll
    for (int off = 16; off; off >>= 1) ssum += __shfl_xor(ssum, off, 32);
    sc[tid] = e / ssum;
  }
  __syncthreads();
  float sad = 0.f;
  for (int k2 = 0; k2 < 32; ++k2) sad += sc[k2] * sm[k2 * 129 + tid];
  sa[tid] = sad;
  __syncthreads();
  float o = bv[tid];
  for (int d = 0; d < 128; ++d) o += sa[d] * wvT[d * 128 + tid];
  atten[n * 128 + tid] = o + 0.1f * ego[n * 128 + tid];
}

// ------------------------------------------------------- fusion -------------
__global__ __launch_bounds__(128) void k_fuse1(const float* __restrict__ allemb,
                                               const float* __restrict__ atten,
                                               const float* __restrict__ fw,
                                               const float* __restrict__ fb,
                                               float* __restrict__ z1,
                                               float* __restrict__ z2,
                                               float* __restrict__ cs1,
                                               float* __restrict__ cs2) {
  __shared__ float fwT[128 * 129];
  __shared__ float xr[128], ar[128];
  const int tid = threadIdx.x;
  for (int it = 0; it < 128; ++it) fwT[tid * 129 + it] = fw[it * 128 + tid];
  const float fbj = fb[tid];
  float ls1 = 0.f, ls2 = 0.f;
  const int r0 = blockIdx.x * 64;
  for (int rr = 0; rr < 64; ++rr) {
    const int r = r0 + rr;
    __syncthreads();
    xr[tid] = allemb[r * 128 + tid];
    ar[tid] = atten[r * 128 + tid];
    __syncthreads();
    float a1 = fbj, a2 = fbj;
    for (int d = 0; d < 128; ++d) {
      const float wgt = fwT[d * 129 + tid];
      a1 += xr[d] * wgt;
      a2 += ar[d] * wgt;
    }
    const float t1 = tanhf(a1), t2 = tanhf(a2);
    z1[r * 128 + tid] = t1;
    z2[r * 128 + tid] = t2;
    ls1 += expf(t1 - 1.0f);
    ls2 += expf(t2 - 1.0f);
  }
  atomicAdd(&cs1[tid], ls1);
  atomicAdd(&cs2[tid], ls2);
}

__global__ void k_fuse2(const float* __restrict__ allemb, const float* __restrict__ atten,
                        const float* __restrict__ z1, const float* __restrict__ z2,
                        const float* __restrict__ cs1, const float* __restrict__ cs2,
                        float* __restrict__ fusion) {
  const int i = blockIdx.x * 256 + threadIdx.x;
  const int j = i & 127;
  const float a1 = expf(z1[i] - 1.0f) / cs1[j];
  const float a2 = expf(z2[i] - 1.0f) / cs2[j];
  fusion[i] = a1 * allemb[i] + a2 * atten[i];
}

// ---------------------------------------------------------------- launch ----
extern "C" void kernel_launch(void* const* d_in, const int* in_sizes, int n_in,
                              void* d_out, int out_size, void* d_ws, size_t ws_size,
                              hipStream_t stream) {
  (void)in_sizes; (void)n_in; (void)out_size; (void)ws_size;
  const float* user = (const float*)d_in[0];
  const float* item = (const float*)d_in[1];
  const int* adj_rows = (const int*)d_in[2];
  const int* adj_cols = (const int*)d_in[3];
  const float* adj_vals = (const float*)d_in[4];
  const float* wq = (const float*)d_in[5];
  const float* bq = (const float*)d_in[6];
  const float* wk = (const float*)d_in[7];
  const float* wv = (const float*)d_in[9];
  const float* bv = (const float*)d_in[10];
  const float* fw = (const float*)d_in[11];
  const float* fb = (const float*)d_in[12];

  float* out = (float*)d_out;
  float* allemb = out;                    // [N,D]
  float* atten = out + (size_t)N_ * D_;   // [N,D]
  float* fusion = out + (size_t)2 * N_ * D_;

  char* ws = (char*)d_ws;
  size_t off = 0;
  auto alloc = [&](size_t bytes) { char* p = ws + off; off += (bytes + 255) & ~(size_t)255; return p; };
  float* ego_a = (float*)alloc((size_t)N_ * D_ * 4);
  float* ego_b = (float*)alloc((size_t)N_ * D_ * 4);
  float* qkbuf = (float*)alloc((size_t)N_ * D_ * 4);
  u16* Gh = (u16*)alloc((size_t)N_ * D_ * 2);
  u16* Gl = (u16*)alloc((size_t)N_ * D_ * 2);
  u16* XTh = (u16*)alloc((size_t)N_ * D_ * 2);
  u16* XTl = (u16*)alloc((size_t)N_ * D_ * 2);
  int2* gbuf = (int2*)alloc((size_t)N_ * CAP_ * 8);  // (col,val) pairs (aliased by z1)
  float* z1 = (float*)gbuf;                          // lifetimes disjoint
  float* z2 = (float*)alloc((size_t)N_ * D_ * 4);
  int* topk_idx = (int*)alloc((size_t)N_ * 32 * 4);
  int* ccol = (int*)alloc((size_t)E_ * 4);
  float* cval = (float*)alloc((size_t)E_ * 4);
  int* cnt = (int*)alloc((size_t)N_ * 4);
  int* row_ptr = (int*)alloc((size_t)(N_ + 1) * 4);
  int* cursor = (int*)alloc((size_t)N_ * 4);
  float* M = (float*)alloc(128 * 128 * 4);
  float* bqk = (float*)alloc(128 * 4);
  float* wvT = (float*)alloc(128 * 128 * 4);
  float* cs1 = (float*)alloc(128 * 4);
  float* cs2 = (float*)alloc(128 * 4);
  float* C2 = (float*)alloc(128 * 128 * 4);
  float* svec = (float*)alloc(128 * 4);
  float* tau = (float*)alloc((size_t)N_ * 4);
  int* gcount = (int*)alloc((size_t)N_ * 4);
  int* failq = (int*)alloc(64 * 4);
  int* failn = (int*)alloc(4);
  double* fsim = (double*)alloc((size_t)64 * N_ * 8);

  k_init<<<64, 256, 0, stream>>>(wq, wk, bq, wv, M, bqk, wvT, cnt, cs1, cs2, C2, svec, gcount, failn);
  k_concat<<<8192, 256, 0, stream>>>(user, item, ego_a);
  k_hist<<<2048, 256, 0, stream>>>(adj_rows, cnt);
  k_scan<<<1, 1024, 0, stream>>>(cnt, row_ptr, cursor);
  k_scatter<<<2048, 256, 0, stream>>>(adj_rows, adj_cols, adj_vals, cursor, ccol, cval);

  k_spmm<<<N_, 128, 0, stream>>>(ego_a, ego_b, allemb, row_ptr, ccol, cval, 1);
  k_spmm<<<N_, 128, 0, stream>>>(ego_b, ego_a, allemb, row_ptr, ccol, cval, 0);
  k_spmm<<<N_, 128, 0, stream>>>(ego_a, ego_b, allemb, row_ptr, ccol, cval, 0);
  // ego3 = ego_b
  k_div3<<<8192, 256, 0, stream>>>(allemb);

  k_split_t<<<256, 256, 0, stream>>>(ego_b, Gh, Gl, XTh, XTl, svec);
  k_c2mfma<<<32, 256, 0, stream>>>(XTh, XTl, C2);
  k_tau<<<N_, 128, 0, stream>>>(ego_b, C2, svec, tau);

  k_qk<<<512, 128, 0, stream>>>(ego_b, M, bqk, qkbuf);
  k_simmfma<<<2048, 256, 0, stream>>>(Gh, Gl, tau, gcount, gbuf);
  k_check<<<64, 256, 0, stream>>>(gcount, failq, failn);
  k_refine<<<4096, 256, 0, stream>>>(gcount, gbuf, topk_idx);
  k_fallback<<<64, 256, 0, stream>>>(ego_b, failq, failn, fsim, topk_idx);
  k_attn<<<N_, 128, 0, stream>>>(ego_b, qkbuf, topk_idx, wvT, bv, atten);

  k_fuse1<<<256, 128, 0, stream>>>(allemb, atten, fw, fb, z1, z2, cs1, cs2);
  k_fuse2<<<8192, 256, 0, stream>>>(allemb, atten, z1, z2, cs1, cs2, fusion);
}